// Round 1
// baseline (285.837 us; speedup 1.0000x reference)
//
#include <hip/hip_runtime.h>
#include <math.h>

#define LBL 26
#define MM  14
#define FF  128
#define HH  16
#define WW  8
#define KSZ 5
#define WPB 16   // words per block

// ---------------- kernel 1: fold conv into emission weights ----------------
// W2[l][q] = sum_{ky,kx} K[ky,kx] * W[l][qy-ky+2, qx-kx+2]   (valid range)
// c[l]     = b * sum_f W[l][f]
__global__ void prep_kernel(const float* __restrict__ K,
                            const float* __restrict__ b,
                            const float* __restrict__ W,
                            float* __restrict__ w2,
                            float* __restrict__ cvec) {
    int idx = blockIdx.x * blockDim.x + threadIdx.x;
    int stride = gridDim.x * blockDim.x;
    for (int o = idx; o < LBL * FF; o += stride) {
        int l = o / FF, f = o % FF;
        int qy = f / WW, qx = f % WW;
        double acc = 0.0;
        for (int ky = 0; ky < KSZ; ++ky) {
            int y = qy - ky + 2;
            if (y < 0 || y >= HH) continue;
            for (int kx = 0; kx < KSZ; ++kx) {
                int x = qx - kx + 2;
                if (x < 0 || x >= WW) continue;
                acc += (double)K[ky * KSZ + kx] * (double)W[l * FF + y * WW + x];
            }
        }
        w2[o] = (float)acc;
    }
    for (int l = idx; l < LBL; l += stride) {
        double s = 0.0;
        for (int f = 0; f < FF; ++f) s += (double)W[l * FF + f];
        cvec[l] = (float)(s * (double)b[0]);
    }
}

// ---------------- kernel 2: scores + Viterbi decode ----------------
__global__ __launch_bounds__(256) void crf_kernel(const float* __restrict__ X,
                                                  const float* __restrict__ T,
                                                  const float* __restrict__ w2,
                                                  const float* __restrict__ cvec,
                                                  int* __restrict__ out) {
    __shared__ float s_lds[WPB * MM * LBL];  // per-word emission scores
    __shared__ float T_lds[LBL * LBL];

    const int tid = threadIdx.x;
    const int blk = blockIdx.x;

    for (int i = tid; i < LBL * LBL; i += 256) T_lds[i] = T[i];

    // ---- phase 1: one thread per letter, 26 scores in registers ----
    if (tid < WPB * MM) {
        const int letter = blk * (WPB * MM) + tid;
        const float* xp = X + (size_t)letter * FF;
        float acc[LBL];
#pragma unroll
        for (int l = 0; l < LBL; ++l) acc[l] = cvec[l];
        for (int fb = 0; fb < FF / 4; ++fb) {
            const float4 xv = *(const float4*)(xp + fb * 4);
#pragma unroll
            for (int l = 0; l < LBL; ++l) {
                const float4 wv = *(const float4*)(w2 + l * FF + fb * 4);  // wave-uniform
                acc[l] = fmaf(xv.x, wv.x, acc[l]);
                acc[l] = fmaf(xv.y, wv.y, acc[l]);
                acc[l] = fmaf(xv.z, wv.z, acc[l]);
                acc[l] = fmaf(xv.w, wv.w, acc[l]);
            }
        }
#pragma unroll
        for (int l = 0; l < LBL; ++l) s_lds[tid * LBL + l] = acc[l];
    }
    __syncthreads();

    // ---- phase 2: Viterbi, 32 lanes per word (j = next-label lane) ----
    const int lane = tid & 63;
    const int wave = tid >> 6;
    const int half = (lane >> 5);
    const int j = lane & 31;
    const int jc = (j < LBL) ? j : 0;

    float tcol[LBL];  // T[:, j] in registers
#pragma unroll
    for (int i = 0; i < LBL; ++i) tcol[i] = T_lds[i * LBL + jc];

    for (int pass = 0; pass < WPB / 8; ++pass) {
        const int wi = pass * 8 + wave * 2 + half;
        const int word = blk * WPB + wi;
        const float* sw = s_lds + wi * MM * LBL;

        float v = (j < LBL) ? sw[j] : -INFINITY;
        unsigned bp_pack[4] = {0u, 0u, 0u, 0u};

        for (int t = 1; t < MM; ++t) {
            float best = -INFINITY;
            int bi = 0;
#pragma unroll
            for (int i = 0; i < LBL; ++i) {
                const float vi = __shfl(v, (lane & 32) | i, 64);
                const float val = vi + tcol[i];
                if (val > best) { best = val; bi = i; }  // first-max wins
            }
            v = (j < LBL) ? (best + sw[t * LBL + j]) : -INFINITY;
            const int k = t - 1;
            bp_pack[k >> 2] |= (unsigned)bi << ((k & 3) * 8);
        }

        // argmax over j of final v (within the 32-lane half), first occurrence
        float best = v;
        int bidx = (j < LBL) ? j : 999;
#pragma unroll
        for (int d = 1; d < 32; d <<= 1) {
            const float ov = __shfl_xor(best, d, 64);
            const int oi = __shfl_xor(bidx, d, 64);
            if (ov > best || (ov == best && oi < bidx)) { best = ov; bidx = oi; }
        }

        // backtrack (cur is uniform within the half; all lanes shuffle, lane j==0 stores)
        int cur = bidx;
        if (j == 0) out[word * MM + (MM - 1)] = cur;
        for (int k = MM - 2; k >= 0; --k) {
            const unsigned packed = __shfl(bp_pack[k >> 2], (lane & 32) | cur, 64);
            cur = (int)((packed >> ((k & 3) * 8)) & 0xffu);
            if (j == 0) out[word * MM + k] = cur;
        }
    }
}

extern "C" void kernel_launch(void* const* d_in, const int* in_sizes, int n_in,
                              void* d_out, int out_size, void* d_ws, size_t ws_size,
                              hipStream_t stream) {
    const float* X = (const float*)d_in[0];
    const float* K = (const float*)d_in[1];
    const float* b = (const float*)d_in[2];
    const float* W = (const float*)d_in[3];
    const float* T = (const float*)d_in[4];
    int* out = (int*)d_out;

    float* w2 = (float*)d_ws;                 // 26*128 floats
    float* cvec = w2 + LBL * FF;              // 26 floats

    prep_kernel<<<(LBL * FF + 255) / 256, 256, 0, stream>>>(K, b, W, w2, cvec);

    const int B = in_sizes[0] / (MM * FF);    // 32768
    crf_kernel<<<B / WPB, 256, 0, stream>>>(X, T, w2, cvec, out);
}

// Round 2
// 157.455 us; speedup vs baseline: 1.8154x; 1.8154x over previous
//
#include <hip/hip_runtime.h>
#include <math.h>

#define LBL 26
#define MM  14
#define FF  128
#define HH  16
#define WW  8
#define KSZ 5
#define WPB 16              // words per block
#define LPB (WPB * MM)      // 224 letters per block
#define NITER 8             // 128 features / 16 per chunk

// ---------------- kernel 1: fold conv into emission weights ----------------
__global__ void prep_kernel(const float* __restrict__ K,
                            const float* __restrict__ b,
                            const float* __restrict__ W,
                            float* __restrict__ w2,
                            float* __restrict__ cvec) {
    int idx = blockIdx.x * blockDim.x + threadIdx.x;
    int stride = gridDim.x * blockDim.x;
    for (int o = idx; o < LBL * FF; o += stride) {
        int l = o / FF, f = o % FF;
        int qy = f / WW, qx = f % WW;
        double acc = 0.0;
        for (int ky = 0; ky < KSZ; ++ky) {
            int y = qy - ky + 2;
            if (y < 0 || y >= HH) continue;
            for (int kx = 0; kx < KSZ; ++kx) {
                int x = qx - kx + 2;
                if (x < 0 || x >= WW) continue;
                acc += (double)K[ky * KSZ + kx] * (double)W[l * FF + y * WW + x];
            }
        }
        w2[o] = (float)acc;
    }
    for (int l = idx; l < LBL; l += stride) {
        double s = 0.0;
        for (int f = 0; f < FF; ++f) s += (double)W[l * FF + f];
        cvec[l] = (float)(s * (double)b[0]);
    }
}

// ---------------- kernel 2: scores + Viterbi decode ----------------
__global__ __launch_bounds__(256) void crf_kernel(const float* __restrict__ X,
                                                  const float* __restrict__ T,
                                                  const float* __restrict__ w2,
                                                  const float* __restrict__ cvec,
                                                  int* __restrict__ out) {
    __shared__ float4 tile[LPB * 4];            // 14336 B: 16-feature slice of 224 letters (swizzled)
    __shared__ float  s_lds[WPB * MM * LBL];    // 23296 B: emission scores
    __shared__ float  v_lds[WPB * 32];          // 2048 B: Viterbi v-vectors

    const int tid = threadIdx.x;
    const int blk = blockIdx.x;
    const float4* X4 = (const float4*)X + (size_t)blk * LPB * (FF / 4);
    const float4* W4 = (const float4*)w2;

    // ---- phase 1: scores, feature-chunked through LDS ----
    float acc[LBL];
    if (tid < LPB) {
#pragma unroll
        for (int l = 0; l < LBL; ++l) acc[l] = cvec[l];
    }

    // staging chunk ids (16B units): c = k*256 + tid, letter = c>>2, sub = c&3
    const int c0 = tid, c1 = tid + 256, c2 = tid + 512, c3 = tid + 768;
    float4 st0, st1, st2, st3;

    // prologue: issue chunk 0 loads
    st0 = X4[(c0 >> 2) * 32 + (c0 & 3)];
    st1 = X4[(c1 >> 2) * 32 + (c1 & 3)];
    st2 = X4[(c2 >> 2) * 32 + (c2 & 3)];
    if (tid < 128) st3 = X4[(c3 >> 2) * 32 + (c3 & 3)];

    for (int iter = 0; iter < NITER; ++iter) {
        // write staged chunk into swizzled tile
        tile[(c0 >> 2) * 4 + ((c0 & 3) ^ ((c0 >> 2) & 3))] = st0;
        tile[(c1 >> 2) * 4 + ((c1 & 3) ^ ((c1 >> 2) & 3))] = st1;
        tile[(c2 >> 2) * 4 + ((c2 & 3) ^ ((c2 >> 2) & 3))] = st2;
        if (tid < 128) tile[(c3 >> 2) * 4 + ((c3 & 3) ^ ((c3 >> 2) & 3))] = st3;
        __syncthreads();

        // issue next chunk's loads (in flight during compute)
        if (iter + 1 < NITER) {
            const int ofs = (iter + 1) * 4;
            st0 = X4[(c0 >> 2) * 32 + ofs + (c0 & 3)];
            st1 = X4[(c1 >> 2) * 32 + ofs + (c1 & 3)];
            st2 = X4[(c2 >> 2) * 32 + ofs + (c2 & 3)];
            if (tid < 128) st3 = X4[(c3 >> 2) * 32 + ofs + (c3 & 3)];
        }

        if (tid < LPB) {
            const float4 xv0 = tile[tid * 4 + (0 ^ (tid & 3))];
            const float4 xv1 = tile[tid * 4 + (1 ^ (tid & 3))];
            const float4 xv2 = tile[tid * 4 + (2 ^ (tid & 3))];
            const float4 xv3 = tile[tid * 4 + (3 ^ (tid & 3))];
#pragma unroll
            for (int l = 0; l < LBL; ++l) {
                const float4 w0 = W4[l * 32 + iter * 4 + 0];   // uniform -> s_load
                const float4 w1 = W4[l * 32 + iter * 4 + 1];
                const float4 w2v = W4[l * 32 + iter * 4 + 2];
                const float4 w3 = W4[l * 32 + iter * 4 + 3];
                float a = acc[l];
                a = fmaf(xv0.x, w0.x, a); a = fmaf(xv0.y, w0.y, a);
                a = fmaf(xv0.z, w0.z, a); a = fmaf(xv0.w, w0.w, a);
                a = fmaf(xv1.x, w1.x, a); a = fmaf(xv1.y, w1.y, a);
                a = fmaf(xv1.z, w1.z, a); a = fmaf(xv1.w, w1.w, a);
                a = fmaf(xv2.x, w2v.x, a); a = fmaf(xv2.y, w2v.y, a);
                a = fmaf(xv2.z, w2v.z, a); a = fmaf(xv2.w, w2v.w, a);
                a = fmaf(xv3.x, w3.x, a); a = fmaf(xv3.y, w3.y, a);
                a = fmaf(xv3.z, w3.z, a); a = fmaf(xv3.w, w3.w, a);
                acc[l] = a;
            }
        }
        __syncthreads();
    }

    // write scores to LDS
    if (tid < LPB) {
#pragma unroll
        for (int l = 0; l < LBL; ++l) s_lds[tid * LBL + l] = acc[l];
    }
    __syncthreads();

    // ---- phase 2: Viterbi, 32 lanes per word, v-vector via LDS broadcast ----
    const int lane = tid & 63;
    const int wvid = tid >> 6;
    const int half = lane >> 5;
    const int j = lane & 31;
    const int jc = (j < LBL) ? j : 0;

    float tcol[LBL];  // T[:, j]
#pragma unroll
    for (int i = 0; i < LBL; ++i) tcol[i] = T[i * LBL + jc];

    for (int pass = 0; pass < 2; ++pass) {
        const int wi = pass * 8 + wvid * 2 + half;
        const int word = blk * WPB + wi;
        const float* sw = s_lds + wi * MM * LBL;
        float* vb = v_lds + wi * 32;

        float v = (j < LBL) ? sw[j] : -INFINITY;
        if (j < LBL) vb[j] = v;
        unsigned bp_pack[4] = {0u, 0u, 0u, 0u};

#pragma unroll
        for (int t = 1; t < MM; ++t) {
            float best = -INFINITY;
            int bi = 0;
#define VCHK(vexpr, idx) { const float val = (vexpr) + tcol[idx]; \
                           if (val > best) { best = val; bi = idx; } }
            {
                float4 vv;
                vv = *(const float4*)(vb + 0);
                VCHK(vv.x, 0) VCHK(vv.y, 1) VCHK(vv.z, 2) VCHK(vv.w, 3)
                vv = *(const float4*)(vb + 4);
                VCHK(vv.x, 4) VCHK(vv.y, 5) VCHK(vv.z, 6) VCHK(vv.w, 7)
                vv = *(const float4*)(vb + 8);
                VCHK(vv.x, 8) VCHK(vv.y, 9) VCHK(vv.z, 10) VCHK(vv.w, 11)
                vv = *(const float4*)(vb + 12);
                VCHK(vv.x, 12) VCHK(vv.y, 13) VCHK(vv.z, 14) VCHK(vv.w, 15)
                vv = *(const float4*)(vb + 16);
                VCHK(vv.x, 16) VCHK(vv.y, 17) VCHK(vv.z, 18) VCHK(vv.w, 19)
                vv = *(const float4*)(vb + 20);
                VCHK(vv.x, 20) VCHK(vv.y, 21) VCHK(vv.z, 22) VCHK(vv.w, 23)
                vv = *(const float4*)(vb + 24);
                VCHK(vv.x, 24) VCHK(vv.y, 25)
            }
#undef VCHK
            v = (j < LBL) ? (best + sw[t * LBL + j]) : -INFINITY;
            if (j < LBL) vb[j] = v;
            const int k = t - 1;
            bp_pack[k >> 2] |= (unsigned)bi << ((k & 3) * 8);
        }

        // argmax over j of final v (within 32-lane half), first occurrence
        float best = v;
        int bidx = (j < LBL) ? j : 999;
#pragma unroll
        for (int d = 1; d < 32; d <<= 1) {
            const float ov = __shfl_xor(best, d, 64);
            const int oi = __shfl_xor(bidx, d, 64);
            if (ov > best || (ov == best && oi < bidx)) { best = ov; bidx = oi; }
        }

        // backtrack
        int cur = bidx;
        if (j == 0) out[word * MM + (MM - 1)] = cur;
#pragma unroll
        for (int k = MM - 2; k >= 0; --k) {
            const unsigned packed = __shfl(bp_pack[k >> 2], (lane & 32) | cur, 64);
            cur = (int)((packed >> ((k & 3) * 8)) & 0xffu);
            if (j == 0) out[word * MM + k] = cur;
        }
        __syncthreads();  // v_lds / s_lds stay live per pass; keep passes separated
    }
}

extern "C" void kernel_launch(void* const* d_in, const int* in_sizes, int n_in,
                              void* d_out, int out_size, void* d_ws, size_t ws_size,
                              hipStream_t stream) {
    const float* X = (const float*)d_in[0];
    const float* K = (const float*)d_in[1];
    const float* b = (const float*)d_in[2];
    const float* W = (const float*)d_in[3];
    const float* T = (const float*)d_in[4];
    int* out = (int*)d_out;

    float* w2 = (float*)d_ws;                 // 26*128 floats
    float* cvec = w2 + LBL * FF;              // 26 floats

    prep_kernel<<<(LBL * FF + 255) / 256, 256, 0, stream>>>(K, b, W, w2, cvec);

    const int B = in_sizes[0] / (MM * FF);    // 32768
    crf_kernel<<<B / WPB, 256, 0, stream>>>(X, T, w2, cvec, out);
}